// Round 8
// baseline (128.601 us; speedup 1.0000x reference)
//
#include <hip/hip_runtime.h>
#include <math.h>

#define DDIM 4096
#define EDIM 64
#define NROWS 16384
#define MBLK 32
#define KT 64
#define NKT (DDIM / KT)   // 64
#define TOPK_K 8
#define DIGIT_BIAS 0x00808080

typedef int i32x4 __attribute__((ext_vector_type(4)));

// signed-digit int8 decomposition of v: bytes of (v+BIAS)^BIAS are signed
// digits d_p with v = sum d_p * 256^p   (exact for |v| < 2^31 - 2^23)
__device__ __forceinline__ int digits_of(float f) {
  int v = __float2int_rn(f);
  return (v + DIGIT_BIAS) ^ DIGIT_BIAS;
}

__device__ __forceinline__ unsigned perm_b32(unsigned a, unsigned b, unsigned sel) {
#if __has_builtin(__builtin_amdgcn_perm)
  return __builtin_amdgcn_perm(a, b, sel);
#else
  union { unsigned u[2]; unsigned char c[8]; } s; s.u[0] = b; s.u[1] = a;
  unsigned r = 0;
  for (int i = 0; i < 4; ++i) r |= (unsigned)s.c[(sel >> (8*i)) & 7] << (8*i);
  return r;
#endif
}

// ---------------------------------------------------------------------------
// Wr [4096][64] f32 -> 4 int8 digit planes (w*2^36), fragment-major,
// 64-K-tile granular. (verified R4-R7: idx exact)
// ---------------------------------------------------------------------------
__global__ __launch_bounds__(256) void wr_convert(const float* __restrict__ Wr,
                                                  char* __restrict__ wl8) {
  int t = blockIdx.x * 256 + threadIdx.x;    // 16384 threads
  int e = t & 63, k16 = t >> 6;              // 16 k's per thread
  int kt64 = k16 >> 2, kgg = k16 & 3, nf = e >> 4, col = e & 15;
  int D[16];
  #pragma unroll
  for (int j = 0; j < 16; ++j)
    D[j] = digits_of(Wr[(size_t)(k16 * 16 + j) * EDIM + e] * 68719476736.0f); // 2^36
  #pragma unroll
  for (int pl = 0; pl < 4; ++pl) {
    unsigned wv[4];
    #pragma unroll
    for (int g = 0; g < 4; ++g)
      wv[g] = ((unsigned)((D[4*g+0] >> (8*pl)) & 255))
            | ((unsigned)((D[4*g+1] >> (8*pl)) & 255) << 8)
            | ((unsigned)((D[4*g+2] >> (8*pl)) & 255) << 16)
            | ((unsigned)((D[4*g+3] >> (8*pl)) & 255) << 24);
    i32x4 val = {(int)wv[0], (int)wv[1], (int)wv[2], (int)wv[3]};
    *(i32x4*)(wl8 + (size_t)pl * 262144 + (size_t)(kt64 * 4 + nf) * 1024
              + (size_t)(kgg * 16 + col) * 16) = val;
  }
}

// ---------------------------------------------------------------------------
// Fused exact router. 3-buffer depth-3 pipeline with COUNTED vmcnt (T3+T4):
// loads for 2 future tiles stay in flight across barriers; never vmcnt(0)
// in steady state. MBLK=32, KT=64, 512 blocks (2/CU), 72 KiB LDS.
// ---------------------------------------------------------------------------
__global__ __launch_bounds__(512, 4) void router_fused(
    const float* __restrict__ x, const char* __restrict__ wl8,
    const float* __restrict__ br,
    float* __restrict__ out_scores, float* __restrict__ out_idx) {
  __shared__ __align__(16) char smem[3][24576];   // per buf: [W 16K | x 8K]

  const int tid  = threadIdx.x;
  const int lane = tid & 63;
  const int w    = tid >> 6;          // 0..7
  const int mw   = w >> 2;            // 0..1  (16-row band)
  const int nw   = w & 3;             // 0..3  (16-col band)
  const int kg   = lane >> 4;
  const int row0 = blockIdx.x * MBLK;
  const int row_l = mw * 16 + (lane & 15);
  const int srow = w * 4 + (lane >> 4);     // staging row for x
  const float bias = br[nw * 16 + (lane & 15)];

  i32x4 acc[5] = {};   // digit-weight classes s6..s2

  auto stage = [&](int t, int b) {    // 3 global_load_lds per wave per tile
    #pragma unroll
    for (int i = 0; i < 2; ++i) {
      int c = w * 2 + i;              // W: chunk = plane*4 + nf
      int plane = c >> 2, nf = c & 3;
      const char* src = wl8 + (size_t)plane * 262144 +
                        (size_t)(t * 4 + nf) * 1024 + (size_t)lane * 16;
      __builtin_amdgcn_global_load_lds(
          (const __attribute__((address_space(1))) unsigned int*)(const void*)src,
          (__attribute__((address_space(3))) unsigned int*)(void*)&smem[b][c * 1024],
          16, 0, 0);
    }
    {
      int cc = lane & 15;             // x: LDS linear, source col XOR-swizzled
      const float* src = x + (size_t)(row0 + srow) * DDIM + t * KT
                           + ((cc ^ (srow & 7)) << 2);
      __builtin_amdgcn_global_load_lds(
          (const __attribute__((address_space(1))) unsigned int*)(const void*)src,
          (__attribute__((address_space(3))) unsigned int*)(void*)
              &smem[b][16384 + w * 1024],
          16, 0, 0);
    }
  };

  auto compute = [&](int b) {
    const char* Wb = smem[b];
    const char* Xb = smem[b] + 16384;
    float4 xv[4];
    #pragma unroll
    for (int c = 0; c < 4; ++c) {
      int chunk = (kg * 4 + c) ^ (row_l & 7);
      xv[c] = *(const float4*)(Xb + row_l * 256 + chunk * 16);
    }
    i32x4 a0, a1, a2, a3;             // x * 2^25 -> 4 digit planes
    #pragma unroll
    for (int g = 0; g < 4; ++g) {
      float4 v = xv[g];
      unsigned f0 = (unsigned)digits_of(v.x * 33554432.0f);
      unsigned f1 = (unsigned)digits_of(v.y * 33554432.0f);
      unsigned f2 = (unsigned)digits_of(v.z * 33554432.0f);
      unsigned f3 = (unsigned)digits_of(v.w * 33554432.0f);
      unsigned zl01 = perm_b32(f1, f0, 0x05010400u);
      unsigned zh01 = perm_b32(f1, f0, 0x07030602u);
      unsigned zl23 = perm_b32(f3, f2, 0x05010400u);
      unsigned zh23 = perm_b32(f3, f2, 0x07030602u);
      a0[g] = (int)perm_b32(zl23, zl01, 0x05040100u);
      a1[g] = (int)perm_b32(zl23, zl01, 0x07060302u);
      a2[g] = (int)perm_b32(zh23, zh01, 0x05040100u);
      a3[g] = (int)perm_b32(zh23, zh01, 0x07060302u);
    }
    i32x4 b0 = *(const i32x4*)(Wb + (0 * 4 + nw) * 1024 + lane * 16);
    i32x4 b1 = *(const i32x4*)(Wb + (1 * 4 + nw) * 1024 + lane * 16);
    i32x4 b2 = *(const i32x4*)(Wb + (2 * 4 + nw) * 1024 + lane * 16);
    i32x4 b3 = *(const i32x4*)(Wb + (3 * 4 + nw) * 1024 + lane * 16);

    acc[0] = __builtin_amdgcn_mfma_i32_16x16x64_i8(a3, b3, acc[0], 0, 0, 0);
    acc[1] = __builtin_amdgcn_mfma_i32_16x16x64_i8(a3, b2, acc[1], 0, 0, 0);
    acc[1] = __builtin_amdgcn_mfma_i32_16x16x64_i8(a2, b3, acc[1], 0, 0, 0);
    acc[2] = __builtin_amdgcn_mfma_i32_16x16x64_i8(a3, b1, acc[2], 0, 0, 0);
    acc[2] = __builtin_amdgcn_mfma_i32_16x16x64_i8(a2, b2, acc[2], 0, 0, 0);
    acc[2] = __builtin_amdgcn_mfma_i32_16x16x64_i8(a1, b3, acc[2], 0, 0, 0);
    acc[3] = __builtin_amdgcn_mfma_i32_16x16x64_i8(a3, b0, acc[3], 0, 0, 0);
    acc[3] = __builtin_amdgcn_mfma_i32_16x16x64_i8(a2, b1, acc[3], 0, 0, 0);
    acc[3] = __builtin_amdgcn_mfma_i32_16x16x64_i8(a1, b2, acc[3], 0, 0, 0);
    acc[3] = __builtin_amdgcn_mfma_i32_16x16x64_i8(a0, b3, acc[3], 0, 0, 0);
    acc[4] = __builtin_amdgcn_mfma_i32_16x16x64_i8(a2, b0, acc[4], 0, 0, 0);
    acc[4] = __builtin_amdgcn_mfma_i32_16x16x64_i8(a1, b1, acc[4], 0, 0, 0);
    acc[4] = __builtin_amdgcn_mfma_i32_16x16x64_i8(a0, b2, acc[4], 0, 0, 0);
  };

  // one pipeline step: counted-vmcnt wait (never 0 until tail), double barrier
  auto step = [&](int t, int b) {
    if (t <= NKT - 3)      asm volatile("s_waitcnt vmcnt(6)" ::: "memory");
    else if (t == NKT - 2) asm volatile("s_waitcnt vmcnt(3)" ::: "memory");
    else                   asm volatile("s_waitcnt vmcnt(0)" ::: "memory");
    __builtin_amdgcn_sched_barrier(0);
    __builtin_amdgcn_s_barrier();        // buf b loaded, all waves agree
    __builtin_amdgcn_sched_barrier(0);
    compute(b);
    asm volatile("s_waitcnt lgkmcnt(0)" ::: "memory");
    __builtin_amdgcn_sched_barrier(0);
    __builtin_amdgcn_s_barrier();        // all waves done reading buf b
    if (t + 3 < NKT) stage(t + 3, b);    // overwrite buf b, loads stay in flight
  };

  stage(0, 0); stage(1, 1); stage(2, 2);  // 9 loads outstanding
  for (int t = 0; t < 63; t += 3) {       // 21 iterations, tiles 0..62
    step(t, 0); step(t + 1, 1); step(t + 2, 2);
  }
  step(63, 0);                            // tail tile

  // ---- epilogue: fp64 combine (weights 2^(8s-61)), top-8, sparse softmax ----
  double* ls = (double*)smem;           // 32 x 64 doubles = 16 KiB
  {
    int cc = nw * 16 + (lane & 15);
    #pragma unroll
    for (int j = 0; j < 4; ++j) {
      int r = mw * 16 + (lane >> 4) * 4 + j;   // C/D: row=(lane>>4)*4+reg
      double lg = (double)acc[0][j] * 0x1p-13 + (double)acc[1][j] * 0x1p-21
                + (double)acc[2][j] * 0x1p-29 + (double)acc[3][j] * 0x1p-37
                + (double)acc[4][j] * 0x1p-45 + (double)bias;
      ls[r * 64 + cc] = lg;
    }
  }
  __syncthreads();

  for (int rr = 0; rr < 4; ++rr) {
    int r = w * 4 + rr;
    double v0 = ls[r * 64 + lane];
    double cur = v0;
    bool sel  = false;
    int myidx = 0;
    double maxv = 0.0;
    #pragma unroll
    for (int k = 0; k < TOPK_K; ++k) {
      double bv = cur;
      int    bi = lane;
      #pragma unroll
      for (int off = 32; off; off >>= 1) {
        double ov = __shfl_xor(bv, off);
        int    oi = __shfl_xor(bi, off);
        if (ov > bv || (ov == bv && oi < bi)) { bv = ov; bi = oi; }
      }
      if (k == 0) maxv = bv;
      if (lane == k) myidx = bi;
      if (lane == bi) { cur = -__builtin_inf(); sel = true; }
    }
    float pv = sel ? expf((float)(v0 - maxv)) : 0.f;
    float ssum = pv;
    #pragma unroll
    for (int off = 32; off; off >>= 1) ssum += __shfl_xor(ssum, off);

    size_t rg = (size_t)row0 + r;
    out_scores[rg * 64 + lane] = pv / ssum;
    if (lane < TOPK_K) out_idx[rg * 8 + lane] = (float)myidx;
  }
}

extern "C" void kernel_launch(void* const* d_in, const int* in_sizes, int n_in,
                              void* d_out, int out_size, void* d_ws, size_t ws_size,
                              hipStream_t stream) {
  const float* x  = (const float*)d_in[0];
  const float* Wr = (const float*)d_in[1];
  const float* br = (const float*)d_in[2];
  // d_in[3] (Wn), d_in[4] (bn): dead code in the reference — intentionally unused.

  char* wl8 = (char*)d_ws;                          // 4 planes x 256 KiB = 1 MiB
  float* out_scores = (float*)d_out;
  float* out_idx    = out_scores + (size_t)NROWS * EDIM;

  wr_convert<<<64, 256, 0, stream>>>(Wr, wl8);
  router_fused<<<NROWS / MBLK, 512, 0, stream>>>(x, wl8, br, out_scores, out_idx);
}

// Round 9
// 123.799 us; speedup vs baseline: 1.0388x; 1.0388x over previous
//
#include <hip/hip_runtime.h>
#include <math.h>

#define DDIM 4096
#define EDIM 64
#define NROWS 16384
#define MBLK 32
#define KT 64
#define NKT 64
#define TOPK_K 8
#define DIGIT_BIAS 0x00808080

typedef int i32x4 __attribute__((ext_vector_type(4)));

// signed-digit int8 decomposition: bytes of (v+BIAS)^BIAS are signed digits
// d_p with v = sum d_p * 256^p (exact for |v| < 2^31 - 2^23)
__device__ __forceinline__ int digits_rn(float f) {
  int v = __float2int_rn(f);
  return (v + DIGIT_BIAS) ^ DIGIT_BIAS;
}
__device__ __forceinline__ int digits_tz(float f) {
  int v = (int)f;                    // trunc cvt: saves v_rndne; noise ~1e-8
  return (v + DIGIT_BIAS) ^ DIGIT_BIAS;
}

__device__ __forceinline__ unsigned perm_b32(unsigned a, unsigned b, unsigned sel) {
#if __has_builtin(__builtin_amdgcn_perm)
  return __builtin_amdgcn_perm(a, b, sel);
#else
  union { unsigned u[2]; unsigned char c[8]; } s; s.u[0] = b; s.u[1] = a;
  unsigned r = 0;
  for (int i = 0; i < 4; ++i) r |= (unsigned)s.c[(sel >> (8*i)) & 7] << (8*i);
  return r;
#endif
}

// ---------------------------------------------------------------------------
// Wr [4096][64] f32 -> 4 int8 digit planes (w*2^36), fragment-major,
// 64-K-tile granular. (verified R4-R8: idx exact) — UNCHANGED
// ---------------------------------------------------------------------------
__global__ __launch_bounds__(256) void wr_convert(const float* __restrict__ Wr,
                                                  char* __restrict__ wl8) {
  int t = blockIdx.x * 256 + threadIdx.x;
  int e = t & 63, k16 = t >> 6;
  int kt64 = k16 >> 2, kgg = k16 & 3, nf = e >> 4, col = e & 15;
  int D[16];
  #pragma unroll
  for (int j = 0; j < 16; ++j)
    D[j] = digits_rn(Wr[(size_t)(k16 * 16 + j) * EDIM + e] * 68719476736.0f);
  #pragma unroll
  for (int pl = 0; pl < 4; ++pl) {
    unsigned wv[4];
    #pragma unroll
    for (int g = 0; g < 4; ++g)
      wv[g] = ((unsigned)((D[4*g+0] >> (8*pl)) & 255))
            | ((unsigned)((D[4*g+1] >> (8*pl)) & 255) << 8)
            | ((unsigned)((D[4*g+2] >> (8*pl)) & 255) << 16)
            | ((unsigned)((D[4*g+3] >> (8*pl)) & 255) << 24);
    i32x4 val = {(int)wv[0], (int)wv[1], (int)wv[2], (int)wv[3]};
    *(i32x4*)(wl8 + (size_t)pl * 262144 + (size_t)(kt64 * 4 + nf) * 1024
              + (size_t)(kgg * 16 + col) * 16) = val;
  }
}

// one pipeline step: single barrier; stage fires early; convert(t+1) overlaps
// MFMA(t) on separate pipes (frags register-double-buffered).
#define STEP(T, SB, RB, AC, BC, AN, BN, VM, DOSTAGE) do {              \
    asm volatile("s_waitcnt vmcnt(" #VM ")" ::: "memory");             \
    __builtin_amdgcn_sched_barrier(0);                                 \
    __builtin_amdgcn_s_barrier();                                      \
    __builtin_amdgcn_sched_barrier(0);                                 \
    if (DOSTAGE) stage((T) + 3, (SB));                                 \
    float4 xv[4];                                                      \
    ldX((RB), xv); ldB((RB), BN);                                      \
    cvtg(xv[0], AN, 0); mf3a(AC, BC);                                  \
    cvtg(xv[1], AN, 1); mf3b(AC, BC);                                  \
    cvtg(xv[2], AN, 2); mf3c(AC, BC);                                  \
    cvtg(xv[3], AN, 3); mf4d(AC, BC);                                  \
    asm volatile("s_waitcnt lgkmcnt(0)" ::: "memory");                 \
    __builtin_amdgcn_sched_barrier(0);                                 \
  } while (0)

// ---------------------------------------------------------------------------
// Fused exact router, per-wave cross-pipe pipeline. 512 blocks x 512 threads,
// 8 waves = 2mw x 4nw; 3-buffer LDS (72 KiB); frag regs double-buffered.
// ---------------------------------------------------------------------------
__global__ __launch_bounds__(512, 4) void router_fused(
    const float* __restrict__ x, const char* __restrict__ wl8,
    const float* __restrict__ br,
    float* __restrict__ out_scores, float* __restrict__ out_idx) {
  __shared__ __align__(16) char smem[3][24576];   // per buf: [W 16K | x 8K]
  char* sb = (char*)smem;

  const int tid  = threadIdx.x;
  const int lane = tid & 63;
  const int w    = tid >> 6;
  const int mw   = w >> 2;
  const int nw   = w & 3;
  const int kg   = lane >> 4;
  const int row0 = blockIdx.x * MBLK;
  const int row_l = mw * 16 + (lane & 15);
  const int srow = w * 4 + (lane >> 4);
  const float bias = br[nw * 16 + (lane & 15)];

  i32x4 acc[5] = {};                // digit-weight classes s6..s2
  i32x4 A0[4], A1[4], B0[4], B1[4]; // double-buffered fragments

  // ---- loop-invariant addressing ----
  const unsigned wrd = (unsigned)(nw * 1024 + lane * 16);          // + p*4096 + RB*24576
  unsigned xrd[4];
  #pragma unroll
  for (int c = 0; c < 4; ++c)
    xrd[c] = 16384u + (unsigned)(row_l * 256) +
             (unsigned)((((kg * 4 + c) ^ (row_l & 7)) << 4));
  const int c0 = w * 2, c1 = w * 2 + 1;
  const char* wsrc0 = wl8 + (size_t)(c0 >> 2) * 262144 + (size_t)(c0 & 3) * 1024 + (size_t)lane * 16;
  const char* wsrc1 = wl8 + (size_t)(c1 >> 2) * 262144 + (size_t)(c1 & 3) * 1024 + (size_t)lane * 16;
  const char* xsrc  = (const char*)x + ((size_t)(row0 + srow)) * (DDIM * 4)
                      + (size_t)((((unsigned)lane & 15) ^ (unsigned)(srow & 7)) << 4);
  char* wdst0 = sb + c0 * 1024;
  char* wdst1 = sb + c1 * 1024;
  char* xdst  = sb + 16384 + w * 1024;

  auto gll = [](const char* src, char* dst) {
    __builtin_amdgcn_global_load_lds(
        (const __attribute__((address_space(1))) unsigned int*)(const void*)src,
        (__attribute__((address_space(3))) unsigned int*)(void*)dst, 16, 0, 0);
  };
  auto stage = [&](int t, int b) {
    gll(wsrc0 + (size_t)t * 4096, wdst0 + b * 24576);
    gll(wsrc1 + (size_t)t * 4096, wdst1 + b * 24576);
    gll(xsrc  + (size_t)t * 256,  xdst  + b * 24576);
  };
  auto ldB = [&](int RB, i32x4 (&Bn)[4]) {
    #pragma unroll
    for (int p = 0; p < 4; ++p)
      Bn[p] = *(const i32x4*)(sb + RB * 24576 + p * 4096 + wrd);
  };
  auto ldX = [&](int RB, float4 (&xv)[4]) {
    #pragma unroll
    for (int c = 0; c < 4; ++c)
      xv[c] = *(const float4*)(sb + RB * 24576 + xrd[c]);
  };
  auto cvtg = [&](const float4& v, i32x4 (&An)[4], int g) {
    unsigned f0 = (unsigned)digits_tz(v.x * 33554432.0f);   // x * 2^25
    unsigned f1 = (unsigned)digits_tz(v.y * 33554432.0f);
    unsigned f2 = (unsigned)digits_tz(v.z * 33554432.0f);
    unsigned f3 = (unsigned)digits_tz(v.w * 33554432.0f);
    unsigned zl01 = perm_b32(f1, f0, 0x05010400u);
    unsigned zh01 = perm_b32(f1, f0, 0x07030602u);
    unsigned zl23 = perm_b32(f3, f2, 0x05010400u);
    unsigned zh23 = perm_b32(f3, f2, 0x07030602u);
    An[0][g] = (int)perm_b32(zl23, zl01, 0x05040100u);
    An[1][g] = (int)perm_b32(zl23, zl01, 0x07060302u);
    An[2][g] = (int)perm_b32(zh23, zh01, 0x05040100u);
    An[3][g] = (int)perm_b32(zh23, zh01, 0x07060302u);
  };
  // 13 MFMAs, round-robin across acc classes (pure int reassociation: exact)
  auto mf3a = [&](i32x4 (&a)[4], i32x4 (&b)[4]) {
    acc[0] = __builtin_amdgcn_mfma_i32_16x16x64_i8(a[3], b[3], acc[0], 0, 0, 0);
    acc[1] = __builtin_amdgcn_mfma_i32_16x16x64_i8(a[3], b[2], acc[1], 0, 0, 0);
    acc[2] = __builtin_amdgcn_mfma_i32_16x16x64_i8(a[3], b[1], acc[2], 0, 0, 0);
  };
  auto mf3b = [&](i32x4 (&a)[4], i32x4 (&b)[4]) {
    acc[3] = __builtin_amdgcn_mfma_i32_16x16x64_i8(a[3], b[0], acc[3], 0, 0, 0);
    acc[4] = __builtin_amdgcn_mfma_i32_16x16x64_i8(a[2], b[0], acc[4], 0, 0, 0);
    acc[1] = __builtin_amdgcn_mfma_i32_16x16x64_i8(a[2], b[3], acc[1], 0, 0, 0);
  };
  auto mf3c = [&](i32x4 (&a)[4], i32x4 (&b)[4]) {
    acc[2] = __builtin_amdgcn_mfma_i32_16x16x64_i8(a[2], b[2], acc[2], 0, 0, 0);
    acc[3] = __builtin_amdgcn_mfma_i32_16x16x64_i8(a[2], b[1], acc[3], 0, 0, 0);
    acc[4] = __builtin_amdgcn_mfma_i32_16x16x64_i8(a[1], b[1], acc[4], 0, 0, 0);
  };
  auto mf4d = [&](i32x4 (&a)[4], i32x4 (&b)[4]) {
    acc[2] = __builtin_amdgcn_mfma_i32_16x16x64_i8(a[1], b[3], acc[2], 0, 0, 0);
    acc[3] = __builtin_amdgcn_mfma_i32_16x16x64_i8(a[1], b[2], acc[3], 0, 0, 0);
    acc[4] = __builtin_amdgcn_mfma_i32_16x16x64_i8(a[0], b[2], acc[4], 0, 0, 0);
    acc[3] = __builtin_amdgcn_mfma_i32_16x16x64_i8(a[0], b[3], acc[3], 0, 0, 0);
  };

  // ---- prologue: fill 3 buffers, convert tile 0 into frag set 0 ----
  stage(0, 0); stage(1, 1); stage(2, 2);
  asm volatile("s_waitcnt vmcnt(6)" ::: "memory");
  __builtin_amdgcn_sched_barrier(0);
  __builtin_amdgcn_s_barrier();
  __builtin_amdgcn_sched_barrier(0);
  {
    float4 xv[4];
    ldX(0, xv); ldB(0, B0);
    cvtg(xv[0], A0, 0); cvtg(xv[1], A0, 1); cvtg(xv[2], A0, 2); cvtg(xv[3], A0, 3);
  }
  asm volatile("s_waitcnt lgkmcnt(0)" ::: "memory");
  __builtin_amdgcn_sched_barrier(0);

  // ---- main: 63 overlapped steps + MFMA-only tail ----
  for (int t = 0; t < 60; t += 6) {
    STEP(t + 0, 0, 1, A0, B0, A1, B1, 3, 1);
    STEP(t + 1, 1, 2, A1, B1, A0, B0, 3, 1);
    STEP(t + 2, 2, 0, A0, B0, A1, B1, 3, 1);
    STEP(t + 3, 0, 1, A1, B1, A0, B0, 3, 1);
    STEP(t + 4, 1, 2, A0, B0, A1, B1, 3, 1);
    STEP(t + 5, 2, 0, A1, B1, A0, B0, 3, 1);
  }
  STEP(60, 0, 1, A0, B0, A1, B1, 3, 1);
  STEP(61, 1, 2, A1, B1, A0, B0, 3, 0);
  STEP(62, 2, 0, A0, B0, A1, B1, 0, 0);
  mf3a(A1, B1); mf3b(A1, B1); mf3c(A1, B1); mf4d(A1, B1);   // tile 63
  __syncthreads();

  // ---- epilogue: fp64 combine (class s: 2^(8s-61)), top-8, sparse softmax ----
  double* ls = (double*)smem;
  {
    int cc = nw * 16 + (lane & 15);
    #pragma unroll
    for (int j = 0; j < 4; ++j) {
      int r = mw * 16 + (lane >> 4) * 4 + j;   // C/D: row=(lane>>4)*4+reg
      double lg = (double)acc[0][j] * 0x1p-13 + (double)acc[1][j] * 0x1p-21
                + (double)acc[2][j] * 0x1p-29 + (double)acc[3][j] * 0x1p-37
                + (double)acc[4][j] * 0x1p-45 + (double)bias;
      ls[r * 64 + cc] = lg;
    }
  }
  __syncthreads();

  for (int rr = 0; rr < 4; ++rr) {
    int r = w * 4 + rr;
    double v0 = ls[r * 64 + lane];
    double cur = v0;
    bool sel  = false;
    int myidx = 0;
    double maxv = 0.0;
    #pragma unroll
    for (int k = 0; k < TOPK_K; ++k) {
      double bv = cur;
      int    bi = lane;
      #pragma unroll
      for (int off = 32; off; off >>= 1) {
        double ov = __shfl_xor(bv, off);
        int    oi = __shfl_xor(bi, off);
        if (ov > bv || (ov == bv && oi < bi)) { bv = ov; bi = oi; }
      }
      if (k == 0) maxv = bv;
      if (lane == k) myidx = bi;
      if (lane == bi) { cur = -__builtin_inf(); sel = true; }
    }
    float pv = sel ? expf((float)(v0 - maxv)) : 0.f;
    float ssum = pv;
    #pragma unroll
    for (int off = 32; off; off >>= 1) ssum += __shfl_xor(ssum, off);

    size_t rg = (size_t)row0 + r;
    out_scores[rg * 64 + lane] = pv / ssum;
    if (lane < TOPK_K) out_idx[rg * 8 + lane] = (float)myidx;
  }
}

extern "C" void kernel_launch(void* const* d_in, const int* in_sizes, int n_in,
                              void* d_out, int out_size, void* d_ws, size_t ws_size,
                              hipStream_t stream) {
  const float* x  = (const float*)d_in[0];
  const float* Wr = (const float*)d_in[1];
  const float* br = (const float*)d_in[2];
  // d_in[3] (Wn), d_in[4] (bn): dead code in the reference — intentionally unused.

  char* wl8 = (char*)d_ws;                          // 4 planes x 256 KiB = 1 MiB
  float* out_scores = (float*)d_out;
  float* out_idx    = out_scores + (size_t)NROWS * EDIM;

  wr_convert<<<64, 256, 0, stream>>>(Wr, wl8);
  router_fused<<<NROWS / MBLK, 512, 0, stream>>>(x, wl8, br, out_scores, out_idx);
}